// Round 12
// baseline (525.565 us; speedup 1.0000x reference)
//
#include <hip/hip_runtime.h>
#include <hip/hip_bf16.h>

#define NN 50000
#define NE 800000
#define NG 64
#define DH 128
#define EPSV 1e-5
#define NBLK_AGG 1000
#define NPB 50            // nodes per agg block: NBLK_AGG*NPB >= NN
#define SCAN_BLK 256
#define SCAN_NBLK ((NN + SCAN_BLK - 1) / SCAN_BLK)   // 196
#define PB_STRIDE 1024    // pblock_t row stride (>= NBLK_AGG)

// ---------------- CSR build (one atomic per edge total) ----------------

// per-dst edge count; off[e] = slot of edge e within its dst bucket
__global__ void edge_count(const int* __restrict__ dst, int* __restrict__ ecnt,
                           int* __restrict__ off) {
    int e = blockIdx.x * 256 + threadIdx.x;
    if (e < NE) off[e] = atomicAdd(&ecnt[dst[e]], 1);
}

// per-block sums of ecnt
__global__ __launch_bounds__(SCAN_BLK) void scan_partial(
    const int* __restrict__ ecnt, int* __restrict__ bsum) {
    int tid = threadIdx.x;
    int i = blockIdx.x * SCAN_BLK + tid;
    int v = (i < NN) ? ecnt[i] : 0;
    __shared__ int sm[SCAN_BLK];
    sm[tid] = v;
    __syncthreads();
    for (int off = SCAN_BLK / 2; off > 0; off >>= 1) {
        if (tid < off) sm[tid] += sm[tid + off];
        __syncthreads();
    }
    if (tid == 0) bsum[blockIdx.x] = sm[0];
}

// rowptr: each block redundantly scans bsum (196 ints) in LDS for its offset,
// then local exclusive scan of its ecnt chunk. (merged scan_bsum + rowptr_write)
__global__ __launch_bounds__(SCAN_BLK) void rowptr_write_f(
    const int* __restrict__ ecnt, const int* __restrict__ bsum,
    int* __restrict__ rowptr) {
    __shared__ int sb[256];
    __shared__ int s[SCAN_BLK];
    int tid = threadIdx.x;
    int bv = (tid < SCAN_NBLK) ? bsum[tid] : 0;
    sb[tid] = bv;
    __syncthreads();
    for (int off = 1; off < 256; off <<= 1) {
        int u = (tid >= off) ? sb[tid - off] : 0;
        __syncthreads();
        sb[tid] += u;
        __syncthreads();
    }
    int boff = (blockIdx.x > 0) ? sb[blockIdx.x - 1] : 0;
    int i = blockIdx.x * SCAN_BLK + tid;
    int v = (i < NN) ? ecnt[i] : 0;
    s[tid] = v;
    __syncthreads();
    for (int off = 1; off < SCAN_BLK; off <<= 1) {
        int u = (tid >= off) ? s[tid - off] : 0;
        __syncthreads();
        s[tid] += u;
        __syncthreads();
    }
    if (i < NN) rowptr[i] = s[tid] - v + boff;
    if (i == 0) rowptr[NN] = NE;   // total edge count is a compile-time constant
}

// place (src, w) into precomputed slots -- NO atomics
__global__ void edge_place2(const int* __restrict__ src, const int* __restrict__ dst,
                            const float* __restrict__ w, const int* __restrict__ rowptr,
                            const int* __restrict__ off, int* __restrict__ csr_src,
                            float* __restrict__ csr_w) {
    int e = blockIdx.x * 256 + threadIdx.x;
    if (e < NE) {
        int pos = rowptr[dst[e]] + off[e];
        csr_src[pos] = src[e];
        csr_w[pos] = w[e];
    }
}

// weighted degree from CSR rows (contiguous, no atomics) -> dinv
__global__ void deg_dinv_csr(const float* __restrict__ csr_w,
                             const int* __restrict__ rowptr,
                             float* __restrict__ dinv) {
    int n = blockIdx.x * 256 + threadIdx.x;
    if (n < NN) {
        float s = 1.0f;   // self-loop weight 1
        int e1 = rowptr[n + 1];
        for (int e = rowptr[n]; e < e1; ++e) s += csr_w[e];
        dinv[n] = 1.0f / sqrtf(s);
    }
}

// ---------------- fused GEMM: (opt BN affine+relu on input) -> 
//    hwb_s[row] = dinv[row] * (act(hin)@W)[row], stored bf16 (RTNE).
//    The dinv prescale folds the symmetric norm so the CSR needs only raw w. ----

__global__ __launch_bounds__(256) void gemm_fused(
    const float* __restrict__ hin, const float* __restrict__ scale,
    const float* __restrict__ shift, const float* __restrict__ W,
    const float* __restrict__ dinv, __hip_bfloat162* __restrict__ hwb)
{
    __shared__ float Ws[DH * DH];   // 64 KB
    __shared__ float hs[32 * DH];   // 16 KB
    int tid = threadIdx.x;

    const float4* Wg = (const float4*)W;
    float4* Ws4 = (float4*)Ws;
#pragma unroll
    for (int i = 0; i < 16; ++i) Ws4[tid + i * 256] = Wg[tid + i * 256];

    int row0 = blockIdx.x * 32;
    float4* hs4 = (float4*)hs;
#pragma unroll
    for (int i = 0; i < 4; ++i) {
        int f4 = tid + i * 256;      // 0..1023
        int r = f4 >> 5;
        int c4 = f4 & 31;
        int row = row0 + r;
        float4 v = make_float4(0.f, 0.f, 0.f, 0.f);
        if (row < NN) {
            v = ((const float4*)hin)[row * 32 + c4];
            if (scale) {
                int c = c4 * 4;
                v.x = fmaxf(v.x * scale[c + 0] + shift[c + 0], 0.f);
                v.y = fmaxf(v.y * scale[c + 1] + shift[c + 1], 0.f);
                v.z = fmaxf(v.z * scale[c + 2] + shift[c + 2], 0.f);
                v.w = fmaxf(v.w * scale[c + 3] + shift[c + 3], 0.f);
            }
        }
        hs4[f4] = v;
    }
    __syncthreads();

    int ct = tid & 31;   // cols ct*4 .. ct*4+3
    int rg = tid >> 5;   // rows rg*4 .. rg*4+3
    float4 acc0 = make_float4(0, 0, 0, 0), acc1 = acc0, acc2 = acc0, acc3 = acc0;

#pragma unroll 8
    for (int k = 0; k < DH; ++k) {
        float4 wv = Ws4[k * 32 + ct];
        float a0 = hs[(rg * 4 + 0) * DH + k];
        float a1 = hs[(rg * 4 + 1) * DH + k];
        float a2 = hs[(rg * 4 + 2) * DH + k];
        float a3 = hs[(rg * 4 + 3) * DH + k];
        acc0.x += a0 * wv.x; acc0.y += a0 * wv.y; acc0.z += a0 * wv.z; acc0.w += a0 * wv.w;
        acc1.x += a1 * wv.x; acc1.y += a1 * wv.y; acc1.z += a1 * wv.z; acc1.w += a1 * wv.w;
        acc2.x += a2 * wv.x; acc2.y += a2 * wv.y; acc2.z += a2 * wv.z; acc2.w += a2 * wv.w;
        acc3.x += a3 * wv.x; acc3.y += a3 * wv.y; acc3.z += a3 * wv.z; acc3.w += a3 * wv.w;
    }

    float4 accs[4] = {acc0, acc1, acc2, acc3};
#pragma unroll
    for (int j = 0; j < 4; ++j) {
        int row = row0 + rg * 4 + j;
        if (row < NN) {
            float di = dinv[row];
            hwb[row * 64 + ct * 2 + 0] =
                __float22bfloat162_rn(make_float2(accs[j].x * di, accs[j].y * di));
            hwb[row * 64 + ct * 2 + 1] =
                __float22bfloat162_rn(make_float2(accs[j].z * di, accs[j].w * di));
        }
    }
}

// ---------------- CSR aggregate: one WAVE per node, bf16x2 per lane (4 B).
//   agg[n] = dinv[n]*(hwb_s[n] + sum w_e*hwb_s[src_e]) + b; 8x unrolled gather.
//   f32 accumulate; BN partial stats written TRANSPOSED: pblock_t[dim][blk]. ------

__global__ __launch_bounds__(512) void agg_csr(
    const __hip_bfloat162* __restrict__ hwb, const int* __restrict__ rowptr,
    const int* __restrict__ csr_src, const float* __restrict__ csr_w,
    const float* __restrict__ b, const float* __restrict__ dinv,
    float2* __restrict__ agg2, double* __restrict__ pblock_t)
{
    int tid = threadIdx.x;
    int lane = tid & 63;
    int w = tid >> 6;            // wave 0..7
    float2 bb = ((const float2*)b)[lane];
    double sx = 0.0, sy = 0.0, qx = 0.0, qy = 0.0;
    int n0 = blockIdx.x * NPB;
    int n1 = min(n0 + NPB, NN);
    for (int node = n0 + w; node < n1; node += 8) {
        float di = dinv[node];
        float2 h = __bfloat1622float2(hwb[node * 64 + lane]);
        float accx = h.x;       // self term (prescaled by dinv[node] already)
        float accy = h.y;
        int e = rowptr[node], e1 = rowptr[node + 1];
        for (; e + 8 <= e1; e += 8) {
            int a0 = csr_src[e + 0];
            int a1 = csr_src[e + 1];
            int a2 = csr_src[e + 2];
            int a3 = csr_src[e + 3];
            int a4 = csr_src[e + 4];
            int a5 = csr_src[e + 5];
            int a6 = csr_src[e + 6];
            int a7 = csr_src[e + 7];
            float w0 = csr_w[e + 0];
            float w1 = csr_w[e + 1];
            float w2 = csr_w[e + 2];
            float w3 = csr_w[e + 3];
            float w4 = csr_w[e + 4];
            float w5 = csr_w[e + 5];
            float w6 = csr_w[e + 6];
            float w7 = csr_w[e + 7];
            float2 v0 = __bfloat1622float2(hwb[a0 * 64 + lane]);
            float2 v1 = __bfloat1622float2(hwb[a1 * 64 + lane]);
            float2 v2 = __bfloat1622float2(hwb[a2 * 64 + lane]);
            float2 v3 = __bfloat1622float2(hwb[a3 * 64 + lane]);
            float2 v4 = __bfloat1622float2(hwb[a4 * 64 + lane]);
            float2 v5 = __bfloat1622float2(hwb[a5 * 64 + lane]);
            float2 v6 = __bfloat1622float2(hwb[a6 * 64 + lane]);
            float2 v7 = __bfloat1622float2(hwb[a7 * 64 + lane]);
            accx += w0 * v0.x; accy += w0 * v0.y;
            accx += w1 * v1.x; accy += w1 * v1.y;
            accx += w2 * v2.x; accy += w2 * v2.y;
            accx += w3 * v3.x; accy += w3 * v3.y;
            accx += w4 * v4.x; accy += w4 * v4.y;
            accx += w5 * v5.x; accy += w5 * v5.y;
            accx += w6 * v6.x; accy += w6 * v6.y;
            accx += w7 * v7.x; accy += w7 * v7.y;
        }
        for (; e + 4 <= e1; e += 4) {
            int a0 = csr_src[e + 0];
            int a1 = csr_src[e + 1];
            int a2 = csr_src[e + 2];
            int a3 = csr_src[e + 3];
            float w0 = csr_w[e + 0];
            float w1 = csr_w[e + 1];
            float w2 = csr_w[e + 2];
            float w3 = csr_w[e + 3];
            float2 v0 = __bfloat1622float2(hwb[a0 * 64 + lane]);
            float2 v1 = __bfloat1622float2(hwb[a1 * 64 + lane]);
            float2 v2 = __bfloat1622float2(hwb[a2 * 64 + lane]);
            float2 v3 = __bfloat1622float2(hwb[a3 * 64 + lane]);
            accx += w0 * v0.x; accy += w0 * v0.y;
            accx += w1 * v1.x; accy += w1 * v1.y;
            accx += w2 * v2.x; accy += w2 * v2.y;
            accx += w3 * v3.x; accy += w3 * v3.y;
        }
        for (; e < e1; ++e) {
            float wn = csr_w[e];
            float2 v = __bfloat1622float2(hwb[csr_src[e] * 64 + lane]);
            accx += wn * v.x; accy += wn * v.y;
        }
        float ox = accx * di + bb.x;
        float oy = accy * di + bb.y;
        agg2[node * 64 + lane] = make_float2(ox, oy);
        sx += (double)ox; qx += (double)ox * (double)ox;
        sy += (double)oy; qy += (double)oy * (double)oy;
    }
    __shared__ double shx[8][64], shy[8][64], qhx[8][64], qhy[8][64];  // 16 KB
    shx[w][lane] = sx; shy[w][lane] = sy;
    qhx[w][lane] = qx; qhy[w][lane] = qy;
    __syncthreads();
    if (tid < 128) {
        int d = tid;
        int ls = d >> 1;
        int comp = d & 1;
        double ssum = 0.0, qsum = 0.0;
#pragma unroll
        for (int ww = 0; ww < 8; ++ww) {
            ssum += comp ? shy[ww][ls] : shx[ww][ls];
            qsum += comp ? qhy[ww][ls] : qhx[ww][ls];
        }
        pblock_t[d * PB_STRIDE + blockIdx.x]         = ssum;
        pblock_t[(128 + d) * PB_STRIDE + blockIdx.x] = qsum;
    }
}

// parallel reduce: one block per feature dim (128 blocks), contiguous row reads
__global__ __launch_bounds__(256) void bn_reduce_t(
    const double* __restrict__ pblock_t, const float* __restrict__ g,
    const float* __restrict__ be, float* __restrict__ scale,
    float* __restrict__ shift)
{
    int d = blockIdx.x;          // 0..127
    int tid = threadIdx.x;
    double s = 0.0, q = 0.0;
    for (int i = tid; i < NBLK_AGG; i += 256) {
        s += pblock_t[d * PB_STRIDE + i];
        q += pblock_t[(128 + d) * PB_STRIDE + i];
    }
    __shared__ double ss[256], qq[256];
    ss[tid] = s; qq[tid] = q;
    __syncthreads();
    for (int off = 128; off > 0; off >>= 1) {
        if (tid < off) { ss[tid] += ss[tid + off]; qq[tid] += qq[tid + off]; }
        __syncthreads();
    }
    if (tid == 0) {
        double mu = ss[0] / (double)NN;
        double ex2 = qq[0] / (double)NN;
        double var = ex2 - mu * mu;
        double sc = (double)g[d] / sqrt(var + (double)EPSV);
        scale[d] = (float)sc;
        shift[d] = (float)((double)be[d] - mu * sc);
    }
}

// ---------------- fused pool (BN3+relu, f64 acc) + MLP head: one block/graph ----

__global__ __launch_bounds__(256) void pool_mlp(
    const float* __restrict__ agg, const float* __restrict__ scale,
    const float* __restrict__ shift, const int* __restrict__ batch,
    const float* __restrict__ Wm1, const float* __restrict__ bm1,
    const float* __restrict__ Wm2, const float* __restrict__ bm2,
    const float* __restrict__ Wm3, const float* __restrict__ bm3,
    const float* __restrict__ Wm4, const float* __restrict__ bm4,
    float* __restrict__ out)
{
    int g = blockIdx.x;
    int tid = threadIdx.x;
    auto lb = [&](int key) {
        int lo = 0, hi = NN;
        while (lo < hi) { int mid = (lo + hi) >> 1; if (batch[mid] < key) lo = mid + 1; else hi = mid; }
        return lo;
    };
    int lo = lb(g), hi = lb(g + 1);

    int d = tid & 127;
    int half = tid >> 7;
    float sc = scale[d], sh = shift[d];
    double acc = 0.0;
    for (int r = lo + half; r < hi; r += 2)
        acc += (double)fmaxf(agg[r * DH + d] * sc + sh, 0.f);

    __shared__ double pm[256];
    __shared__ float za[DH], zb[DH];
    pm[tid] = acc;
    __syncthreads();
    if (tid < 128) {
        double cf = (double)((hi - lo) > 0 ? (hi - lo) : 1);
        za[tid] = (float)((pm[tid] + pm[tid + 128]) / cf);
    }
    __syncthreads();
    float a;
    if (tid < 128) {
        a = bm1[tid];
        for (int k = 0; k < 128; ++k) a += za[k] * Wm1[k * 128 + tid];
        zb[tid] = fmaxf(a, 0.f);
    }
    __syncthreads();
    if (tid < 64) {
        a = bm2[tid];
        for (int k = 0; k < 128; ++k) a += zb[k] * Wm2[k * 64 + tid];
        za[tid] = fmaxf(a, 0.f);
    }
    __syncthreads();
    if (tid < 32) {
        a = bm3[tid];
        for (int k = 0; k < 64; ++k) a += za[k] * Wm3[k * 32 + tid];
        zb[tid] = fmaxf(a, 0.f);
    }
    __syncthreads();
    if (tid < 2) {
        a = bm4[tid];
        for (int k = 0; k < 32; ++k) a += zb[k] * Wm4[k * 2 + tid];
        out[g * 2 + tid] = a;
    }
}

// ---------------- launcher ----------------

extern "C" void kernel_launch(void* const* d_in, const int* in_sizes, int n_in,
                              void* d_out, int out_size, void* d_ws, size_t ws_size,
                              hipStream_t stream) {
    const float* x  = (const float*)d_in[0];
    const int* esrc = (const int*)d_in[1];
    const int* edst = (const int*)d_in[2];
    const float* ew = (const float*)d_in[3];
    const int* batch = (const int*)d_in[4];
    const float* W1 = (const float*)d_in[5];  const float* b1 = (const float*)d_in[6];
    const float* W2 = (const float*)d_in[7];  const float* b2 = (const float*)d_in[8];
    const float* W3 = (const float*)d_in[9];  const float* b3 = (const float*)d_in[10];
    const float* g1 = (const float*)d_in[11]; const float* be1 = (const float*)d_in[12];
    const float* g2 = (const float*)d_in[13]; const float* be2 = (const float*)d_in[14];
    const float* g3 = (const float*)d_in[15]; const float* be3 = (const float*)d_in[16];
    const float* Wm1 = (const float*)d_in[17]; const float* bm1 = (const float*)d_in[18];
    const float* Wm2 = (const float*)d_in[19]; const float* bm2 = (const float*)d_in[20];
    const float* Wm3 = (const float*)d_in[21]; const float* bm3 = (const float*)d_in[22];
    const float* Wm4 = (const float*)d_in[23]; const float* bm4 = (const float*)d_in[24];
    float* out = (float*)d_out;

    char* ws = (char*)d_ws;
    // ---- zeroed region [0, 200192) ----
    int*    ecnt   = (int*)(ws + 0);              // N int (must be zeroed)
    // ---- non-zeroed ----
    float*  dinv   = (float*)(ws + 200192);       // N f32 (fully overwritten)
    float*  scale0 = (float*)(ws + 400384);       // 3 * 256 f32
    int*    bsum   = (int*)(ws + 403456);         // 196 int
    int*    rowptr = (int*)(ws + 404480);         // N+1 int
    int*    csr_src = (int*)(ws + 604672);        // E int
    float*  csr_w   = (float*)(ws + 3804672);     // E f32 (raw edge weights)
    double* pblock_t = (double*)(ws + 7004672);   // 256 * 1024 f64 = 2 MB
    __hip_bfloat162* hwb = (__hip_bfloat162*)(ws + 9101824);  // N*128 bf16 = 12.8 MB
    float*  aggA   = (float*)(ws + 21901824);     // N*128 f32
    float*  aggB   = (float*)(ws + 47501824);     // N*128 f32
    int*    off    = (int*)(ws + 47501824);       // E int -- overlaps aggB (dead
                                                  // during CSR build; aggB first
                                                  // written in layer 2)

    hipMemsetAsync(d_ws, 0, 200192, stream);

    edge_count<<<(NE + 255) / 256, 256, 0, stream>>>(edst, ecnt, off);
    scan_partial<<<SCAN_NBLK, SCAN_BLK, 0, stream>>>(ecnt, bsum);
    rowptr_write_f<<<SCAN_NBLK, SCAN_BLK, 0, stream>>>(ecnt, bsum, rowptr);
    edge_place2<<<(NE + 255) / 256, 256, 0, stream>>>(esrc, edst, ew, rowptr, off,
                                                      csr_src, csr_w);
    deg_dinv_csr<<<(NN + 255) / 256, 256, 0, stream>>>(csr_w, rowptr, dinv);

    const float* Ws_[3] = {W1, W2, W3};
    const float* bs_[3] = {b1, b2, b3};
    const float* gs_[3] = {g1, g2, g3};
    const float* bes_[3] = {be1, be2, be3};
    float* aggs[3] = {aggA, aggB, aggA};
    const int gemm_grid = (NN + 31) / 32;

    const float* curIn = x;
    const float* curScale = nullptr;
    const float* curShift = nullptr;
    for (int l = 0; l < 3; ++l) {
        float* agg = aggs[l];
        gemm_fused<<<gemm_grid, 256, 0, stream>>>(curIn, curScale, curShift,
                                                  Ws_[l], dinv, hwb);
        agg_csr<<<NBLK_AGG, 512, 0, stream>>>(hwb, rowptr, csr_src,
                                              csr_w, bs_[l], dinv,
                                              (float2*)agg, pblock_t);
        float* sc = scale0 + l * 256;
        float* sh = sc + 128;
        bn_reduce_t<<<128, 256, 0, stream>>>(pblock_t, gs_[l], bes_[l], sc, sh);
        curIn = agg;
        curScale = sc;
        curShift = sh;
    }

    pool_mlp<<<NG, 256, 0, stream>>>(aggA, curScale, curShift, batch,
                                     Wm1, bm1, Wm2, bm2, Wm3, bm3, Wm4, bm4, out);
}

// Round 13
// 427.911 us; speedup vs baseline: 1.2282x; 1.2282x over previous
//
#include <hip/hip_runtime.h>
#include <hip/hip_bf16.h>

#define NN 50000
#define NE 800000
#define NG 64
#define DH 128
#define EPSV 1e-5
#define NBLK_AGG 1000
#define NPB 50            // nodes per agg block: NBLK_AGG*NPB >= NN
#define SCAN_BLK 256
#define SCAN_NBLK ((NN + SCAN_BLK - 1) / SCAN_BLK)   // 196
#define PB_STRIDE 1024    // pblock_t row stride (>= NBLK_AGG)

// ---------------- CSR build (one atomic per edge total) ----------------

// per-dst edge count; off[e] = slot of edge e within its dst bucket
__global__ void edge_count(const int* __restrict__ dst, int* __restrict__ ecnt,
                           int* __restrict__ off) {
    int e = blockIdx.x * 256 + threadIdx.x;
    if (e < NE) off[e] = atomicAdd(&ecnt[dst[e]], 1);
}

// per-block sums of ecnt
__global__ __launch_bounds__(SCAN_BLK) void scan_partial(
    const int* __restrict__ ecnt, int* __restrict__ bsum) {
    int tid = threadIdx.x;
    int i = blockIdx.x * SCAN_BLK + tid;
    int v = (i < NN) ? ecnt[i] : 0;
    __shared__ int sm[SCAN_BLK];
    sm[tid] = v;
    __syncthreads();
    for (int off = SCAN_BLK / 2; off > 0; off >>= 1) {
        if (tid < off) sm[tid] += sm[tid + off];
        __syncthreads();
    }
    if (tid == 0) bsum[blockIdx.x] = sm[0];
}

// rowptr: each block redundantly scans bsum (196 ints) in LDS for its offset,
// then local exclusive scan of its ecnt chunk. (merged scan_bsum + rowptr_write)
__global__ __launch_bounds__(SCAN_BLK) void rowptr_write_f(
    const int* __restrict__ ecnt, const int* __restrict__ bsum,
    int* __restrict__ rowptr) {
    __shared__ int sb[256];
    __shared__ int s[SCAN_BLK];
    int tid = threadIdx.x;
    int bv = (tid < SCAN_NBLK) ? bsum[tid] : 0;
    sb[tid] = bv;
    __syncthreads();
    for (int off = 1; off < 256; off <<= 1) {
        int u = (tid >= off) ? sb[tid - off] : 0;
        __syncthreads();
        sb[tid] += u;
        __syncthreads();
    }
    int boff = (blockIdx.x > 0) ? sb[blockIdx.x - 1] : 0;
    int i = blockIdx.x * SCAN_BLK + tid;
    int v = (i < NN) ? ecnt[i] : 0;
    s[tid] = v;
    __syncthreads();
    for (int off = 1; off < SCAN_BLK; off <<= 1) {
        int u = (tid >= off) ? s[tid - off] : 0;
        __syncthreads();
        s[tid] += u;
        __syncthreads();
    }
    if (i < NN) rowptr[i] = s[tid] - v + boff;
    if (i == 0) rowptr[NN] = NE;   // total edge count is a compile-time constant
}

// place (src, w) into precomputed slots -- NO atomics
__global__ void edge_place2(const int* __restrict__ src, const int* __restrict__ dst,
                            const float* __restrict__ w, const int* __restrict__ rowptr,
                            const int* __restrict__ off, int* __restrict__ csr_src,
                            float* __restrict__ csr_w) {
    int e = blockIdx.x * 256 + threadIdx.x;
    if (e < NE) {
        int pos = rowptr[dst[e]] + off[e];
        csr_src[pos] = src[e];
        csr_w[pos] = w[e];
    }
}

// weighted degree from CSR rows (contiguous, no atomics) -> dinv
__global__ void deg_dinv_csr(const float* __restrict__ csr_w,
                             const int* __restrict__ rowptr,
                             float* __restrict__ dinv) {
    int n = blockIdx.x * 256 + threadIdx.x;
    if (n < NN) {
        float s = 1.0f;   // self-loop weight 1
        int e1 = rowptr[n + 1];
        for (int e = rowptr[n]; e < e1; ++e) s += csr_w[e];
        dinv[n] = 1.0f / sqrtf(s);
    }
}

// ---------------- fused GEMM: (opt BN affine+relu on input) ->
//    hwb_s[row] = dinv[row] * (act(hin)@W)[row], stored bf16 (RTNE).
//    The dinv prescale folds the symmetric norm so the CSR needs only raw w. ----

__global__ __launch_bounds__(256) void gemm_fused(
    const float* __restrict__ hin, const float* __restrict__ scale,
    const float* __restrict__ shift, const float* __restrict__ W,
    const float* __restrict__ dinv, __hip_bfloat162* __restrict__ hwb)
{
    __shared__ float Ws[DH * DH];   // 64 KB
    __shared__ float hs[32 * DH];   // 16 KB
    int tid = threadIdx.x;

    const float4* Wg = (const float4*)W;
    float4* Ws4 = (float4*)Ws;
#pragma unroll
    for (int i = 0; i < 16; ++i) Ws4[tid + i * 256] = Wg[tid + i * 256];

    int row0 = blockIdx.x * 32;
    float4* hs4 = (float4*)hs;
#pragma unroll
    for (int i = 0; i < 4; ++i) {
        int f4 = tid + i * 256;      // 0..1023
        int r = f4 >> 5;
        int c4 = f4 & 31;
        int row = row0 + r;
        float4 v = make_float4(0.f, 0.f, 0.f, 0.f);
        if (row < NN) {
            v = ((const float4*)hin)[row * 32 + c4];
            if (scale) {
                int c = c4 * 4;
                v.x = fmaxf(v.x * scale[c + 0] + shift[c + 0], 0.f);
                v.y = fmaxf(v.y * scale[c + 1] + shift[c + 1], 0.f);
                v.z = fmaxf(v.z * scale[c + 2] + shift[c + 2], 0.f);
                v.w = fmaxf(v.w * scale[c + 3] + shift[c + 3], 0.f);
            }
        }
        hs4[f4] = v;
    }
    __syncthreads();

    int ct = tid & 31;   // cols ct*4 .. ct*4+3
    int rg = tid >> 5;   // rows rg*4 .. rg*4+3
    float4 acc0 = make_float4(0, 0, 0, 0), acc1 = acc0, acc2 = acc0, acc3 = acc0;

#pragma unroll 8
    for (int k = 0; k < DH; ++k) {
        float4 wv = Ws4[k * 32 + ct];
        float a0 = hs[(rg * 4 + 0) * DH + k];
        float a1 = hs[(rg * 4 + 1) * DH + k];
        float a2 = hs[(rg * 4 + 2) * DH + k];
        float a3 = hs[(rg * 4 + 3) * DH + k];
        acc0.x += a0 * wv.x; acc0.y += a0 * wv.y; acc0.z += a0 * wv.z; acc0.w += a0 * wv.w;
        acc1.x += a1 * wv.x; acc1.y += a1 * wv.y; acc1.z += a1 * wv.z; acc1.w += a1 * wv.w;
        acc2.x += a2 * wv.x; acc2.y += a2 * wv.y; acc2.z += a2 * wv.z; acc2.w += a2 * wv.w;
        acc3.x += a3 * wv.x; acc3.y += a3 * wv.y; acc3.z += a3 * wv.z; acc3.w += a3 * wv.w;
    }

    float4 accs[4] = {acc0, acc1, acc2, acc3};
#pragma unroll
    for (int j = 0; j < 4; ++j) {
        int row = row0 + rg * 4 + j;
        if (row < NN) {
            float di = dinv[row];
            hwb[row * 64 + ct * 2 + 0] =
                __float22bfloat162_rn(make_float2(accs[j].x * di, accs[j].y * di));
            hwb[row * 64 + ct * 2 + 1] =
                __float22bfloat162_rn(make_float2(accs[j].z * di, accs[j].w * di));
        }
    }
}

// ---------------- CSR aggregate: one WAVE per node, bf16x2 per lane (4 B).
//   agg[n] = dinv[n]*(hwb_s[n] + sum w_e*hwb_s[src_e]) + b; 8x unrolled gather.
//   f32 accumulate; BN partial stats written TRANSPOSED: pblock_t[dim][blk]. ------

__global__ __launch_bounds__(512) void agg_csr(
    const __hip_bfloat162* __restrict__ hwb, const int* __restrict__ rowptr,
    const int* __restrict__ csr_src, const float* __restrict__ csr_w,
    const float* __restrict__ b, const float* __restrict__ dinv,
    float2* __restrict__ agg2, double* __restrict__ pblock_t)
{
    int tid = threadIdx.x;
    int lane = tid & 63;
    int w = tid >> 6;            // wave 0..7
    float2 bb = ((const float2*)b)[lane];
    double sx = 0.0, sy = 0.0, qx = 0.0, qy = 0.0;
    int n0 = blockIdx.x * NPB;
    int n1 = min(n0 + NPB, NN);
    for (int node = n0 + w; node < n1; node += 8) {
        float di = dinv[node];
        float2 h = __bfloat1622float2(hwb[node * 64 + lane]);
        float accx = h.x;       // self term (prescaled by dinv[node] already)
        float accy = h.y;
        int e = rowptr[node], e1 = rowptr[node + 1];
        for (; e + 8 <= e1; e += 8) {
            int a0 = csr_src[e + 0];
            int a1 = csr_src[e + 1];
            int a2 = csr_src[e + 2];
            int a3 = csr_src[e + 3];
            int a4 = csr_src[e + 4];
            int a5 = csr_src[e + 5];
            int a6 = csr_src[e + 6];
            int a7 = csr_src[e + 7];
            float w0 = csr_w[e + 0];
            float w1 = csr_w[e + 1];
            float w2 = csr_w[e + 2];
            float w3 = csr_w[e + 3];
            float w4 = csr_w[e + 4];
            float w5 = csr_w[e + 5];
            float w6 = csr_w[e + 6];
            float w7 = csr_w[e + 7];
            float2 v0 = __bfloat1622float2(hwb[a0 * 64 + lane]);
            float2 v1 = __bfloat1622float2(hwb[a1 * 64 + lane]);
            float2 v2 = __bfloat1622float2(hwb[a2 * 64 + lane]);
            float2 v3 = __bfloat1622float2(hwb[a3 * 64 + lane]);
            float2 v4 = __bfloat1622float2(hwb[a4 * 64 + lane]);
            float2 v5 = __bfloat1622float2(hwb[a5 * 64 + lane]);
            float2 v6 = __bfloat1622float2(hwb[a6 * 64 + lane]);
            float2 v7 = __bfloat1622float2(hwb[a7 * 64 + lane]);
            accx += w0 * v0.x; accy += w0 * v0.y;
            accx += w1 * v1.x; accy += w1 * v1.y;
            accx += w2 * v2.x; accy += w2 * v2.y;
            accx += w3 * v3.x; accy += w3 * v3.y;
            accx += w4 * v4.x; accy += w4 * v4.y;
            accx += w5 * v5.x; accy += w5 * v5.y;
            accx += w6 * v6.x; accy += w6 * v6.y;
            accx += w7 * v7.x; accy += w7 * v7.y;
        }
        for (; e + 4 <= e1; e += 4) {
            int a0 = csr_src[e + 0];
            int a1 = csr_src[e + 1];
            int a2 = csr_src[e + 2];
            int a3 = csr_src[e + 3];
            float w0 = csr_w[e + 0];
            float w1 = csr_w[e + 1];
            float w2 = csr_w[e + 2];
            float w3 = csr_w[e + 3];
            float2 v0 = __bfloat1622float2(hwb[a0 * 64 + lane]);
            float2 v1 = __bfloat1622float2(hwb[a1 * 64 + lane]);
            float2 v2 = __bfloat1622float2(hwb[a2 * 64 + lane]);
            float2 v3 = __bfloat1622float2(hwb[a3 * 64 + lane]);
            accx += w0 * v0.x; accy += w0 * v0.y;
            accx += w1 * v1.x; accy += w1 * v1.y;
            accx += w2 * v2.x; accy += w2 * v2.y;
            accx += w3 * v3.x; accy += w3 * v3.y;
        }
        for (; e < e1; ++e) {
            float wn = csr_w[e];
            float2 v = __bfloat1622float2(hwb[csr_src[e] * 64 + lane]);
            accx += wn * v.x; accy += wn * v.y;
        }
        float ox = accx * di + bb.x;
        float oy = accy * di + bb.y;
        agg2[node * 64 + lane] = make_float2(ox, oy);
        sx += (double)ox; qx += (double)ox * (double)ox;
        sy += (double)oy; qy += (double)oy * (double)oy;
    }
    __shared__ double shx[8][64], shy[8][64], qhx[8][64], qhy[8][64];  // 16 KB
    shx[w][lane] = sx; shy[w][lane] = sy;
    qhx[w][lane] = qx; qhy[w][lane] = qy;
    __syncthreads();
    if (tid < 128) {
        int d = tid;
        int ls = d >> 1;
        int comp = d & 1;
        double ssum = 0.0, qsum = 0.0;
#pragma unroll
        for (int ww = 0; ww < 8; ++ww) {
            ssum += comp ? shy[ww][ls] : shx[ww][ls];
            qsum += comp ? qhy[ww][ls] : qhx[ww][ls];
        }
        pblock_t[d * PB_STRIDE + blockIdx.x]         = ssum;
        pblock_t[(128 + d) * PB_STRIDE + blockIdx.x] = qsum;
    }
}

// parallel reduce: one block per feature dim (128 blocks), contiguous row reads
__global__ __launch_bounds__(256) void bn_reduce_t(
    const double* __restrict__ pblock_t, const float* __restrict__ g,
    const float* __restrict__ be, float* __restrict__ scale,
    float* __restrict__ shift)
{
    int d = blockIdx.x;          // 0..127
    int tid = threadIdx.x;
    double s = 0.0, q = 0.0;
    for (int i = tid; i < NBLK_AGG; i += 256) {
        s += pblock_t[d * PB_STRIDE + i];
        q += pblock_t[(128 + d) * PB_STRIDE + i];
    }
    __shared__ double ss[256], qq[256];
    ss[tid] = s; qq[tid] = q;
    __syncthreads();
    for (int off = 128; off > 0; off >>= 1) {
        if (tid < off) { ss[tid] += ss[tid + off]; qq[tid] += qq[tid + off]; }
        __syncthreads();
    }
    if (tid == 0) {
        double mu = ss[0] / (double)NN;
        double ex2 = qq[0] / (double)NN;
        double var = ex2 - mu * mu;
        double sc = (double)g[d] / sqrt(var + (double)EPSV);
        scale[d] = (float)sc;
        shift[d] = (float)((double)be[d] - mu * sc);
    }
}

// ---------------- pooling (fused BN3+relu), f64 accumulation, 500 blocks --------

#define POOL_CHUNK 100
__global__ __launch_bounds__(256) void pool_k(
    const float* __restrict__ agg, const float* __restrict__ scale,
    const float* __restrict__ shift, const int* __restrict__ batch,
    double* __restrict__ pooled)
{
    int tid = threadIdx.x;
    int d = tid & 127;
    int rl = tid >> 7;
    float sc = scale[d], sh = shift[d];
    int r0 = blockIdx.x * POOL_CHUNK;
    int rend = r0 + POOL_CHUNK;
    if (rend > NN) rend = NN;
    double acc = 0.0;
    int gc = -1;
    for (int r = r0 + rl; r < rend; r += 2) {
        int g = batch[r];
        float v = agg[r * DH + d];
        v = fmaxf(v * sc + sh, 0.f);
        if (g != gc) {
            if (gc >= 0) unsafeAtomicAdd(&pooled[gc * DH + d], acc);
            gc = g; acc = 0.0;
        }
        acc += (double)v;
    }
    if (gc >= 0) unsafeAtomicAdd(&pooled[gc * DH + d], acc);
}

// ---------------- MLP head: one block per graph; graph size via binary search ----

__global__ __launch_bounds__(128) void mlp_k(
    const double* __restrict__ pooled, const int* __restrict__ batch,
    const float* __restrict__ Wm1, const float* __restrict__ bm1,
    const float* __restrict__ Wm2, const float* __restrict__ bm2,
    const float* __restrict__ Wm3, const float* __restrict__ bm3,
    const float* __restrict__ Wm4, const float* __restrict__ bm4,
    float* __restrict__ out)
{
    int g = blockIdx.x;
    int tid = threadIdx.x;
    auto lb = [&](int key) {
        int lo = 0, hi = NN;
        while (lo < hi) { int mid = (lo + hi) >> 1; if (batch[mid] < key) lo = mid + 1; else hi = mid; }
        return lo;
    };
    int cntg = lb(g + 1) - lb(g);
    __shared__ float za[DH], zb[DH];
    float cf = fmaxf((float)cntg, 1.0f);
    za[tid] = (float)(pooled[g * DH + tid] / (double)cf);
    __syncthreads();
    float acc = bm1[tid];
    for (int k = 0; k < 128; ++k) acc += za[k] * Wm1[k * 128 + tid];
    zb[tid] = fmaxf(acc, 0.f);
    __syncthreads();
    if (tid < 64) {
        acc = bm2[tid];
        for (int k = 0; k < 128; ++k) acc += zb[k] * Wm2[k * 64 + tid];
        za[tid] = fmaxf(acc, 0.f);
    }
    __syncthreads();
    if (tid < 32) {
        acc = bm3[tid];
        for (int k = 0; k < 64; ++k) acc += za[k] * Wm3[k * 32 + tid];
        zb[tid] = fmaxf(acc, 0.f);
    }
    __syncthreads();
    if (tid < 2) {
        acc = bm4[tid];
        for (int k = 0; k < 32; ++k) acc += zb[k] * Wm4[k * 2 + tid];
        out[g * 2 + tid] = acc;
    }
}

// ---------------- launcher ----------------

extern "C" void kernel_launch(void* const* d_in, const int* in_sizes, int n_in,
                              void* d_out, int out_size, void* d_ws, size_t ws_size,
                              hipStream_t stream) {
    const float* x  = (const float*)d_in[0];
    const int* esrc = (const int*)d_in[1];
    const int* edst = (const int*)d_in[2];
    const float* ew = (const float*)d_in[3];
    const int* batch = (const int*)d_in[4];
    const float* W1 = (const float*)d_in[5];  const float* b1 = (const float*)d_in[6];
    const float* W2 = (const float*)d_in[7];  const float* b2 = (const float*)d_in[8];
    const float* W3 = (const float*)d_in[9];  const float* b3 = (const float*)d_in[10];
    const float* g1 = (const float*)d_in[11]; const float* be1 = (const float*)d_in[12];
    const float* g2 = (const float*)d_in[13]; const float* be2 = (const float*)d_in[14];
    const float* g3 = (const float*)d_in[15]; const float* be3 = (const float*)d_in[16];
    const float* Wm1 = (const float*)d_in[17]; const float* bm1 = (const float*)d_in[18];
    const float* Wm2 = (const float*)d_in[19]; const float* bm2 = (const float*)d_in[20];
    const float* Wm3 = (const float*)d_in[21]; const float* bm3 = (const float*)d_in[22];
    const float* Wm4 = (const float*)d_in[23]; const float* bm4 = (const float*)d_in[24];
    float* out = (float*)d_out;

    char* ws = (char*)d_ws;
    // ---- zeroed region [0, 265728) ----
    int*    ecnt   = (int*)(ws + 0);              // N int (must be zeroed)
    double* pooled = (double*)(ws + 200192);      // 64*128 f64 (must be zeroed)
    // ---- non-zeroed ----
    float*  dinv   = (float*)(ws + 265728);       // N f32 (fully overwritten)
    float*  scale0 = (float*)(ws + 465984);       // 3 * 256 f32
    int*    bsum   = (int*)(ws + 469056);         // 196 int
    int*    rowptr = (int*)(ws + 471104);         // N+1 int
    int*    csr_src = (int*)(ws + 671744);        // E int
    float*  csr_w   = (float*)(ws + 3871744);     // E f32 (raw edge weights)
    double* pblock_t = (double*)(ws + 7071744);   // 256 * 1024 f64 = 2 MB
    __hip_bfloat162* hwb = (__hip_bfloat162*)(ws + 9323648);  // N*128 bf16 = 12.8 MB
    float*  aggA   = (float*)(ws + 22123648);     // N*128 f32
    float*  aggB   = (float*)(ws + 47723648);     // N*128 f32
    int*    off    = (int*)(ws + 47723648);       // E int -- overlaps aggB (dead
                                                  // during CSR build; aggB first
                                                  // written in layer 2)

    hipMemsetAsync(d_ws, 0, 265728, stream);

    edge_count<<<(NE + 255) / 256, 256, 0, stream>>>(edst, ecnt, off);
    scan_partial<<<SCAN_NBLK, SCAN_BLK, 0, stream>>>(ecnt, bsum);
    rowptr_write_f<<<SCAN_NBLK, SCAN_BLK, 0, stream>>>(ecnt, bsum, rowptr);
    edge_place2<<<(NE + 255) / 256, 256, 0, stream>>>(esrc, edst, ew, rowptr, off,
                                                      csr_src, csr_w);
    deg_dinv_csr<<<(NN + 255) / 256, 256, 0, stream>>>(csr_w, rowptr, dinv);

    const float* Ws_[3] = {W1, W2, W3};
    const float* bs_[3] = {b1, b2, b3};
    const float* gs_[3] = {g1, g2, g3};
    const float* bes_[3] = {be1, be2, be3};
    float* aggs[3] = {aggA, aggB, aggA};
    const int gemm_grid = (NN + 31) / 32;

    const float* curIn = x;
    const float* curScale = nullptr;
    const float* curShift = nullptr;
    for (int l = 0; l < 3; ++l) {
        float* agg = aggs[l];
        gemm_fused<<<gemm_grid, 256, 0, stream>>>(curIn, curScale, curShift,
                                                  Ws_[l], dinv, hwb);
        agg_csr<<<NBLK_AGG, 512, 0, stream>>>(hwb, rowptr, csr_src,
                                              csr_w, bs_[l], dinv,
                                              (float2*)agg, pblock_t);
        float* sc = scale0 + l * 256;
        float* sh = sc + 128;
        bn_reduce_t<<<128, 256, 0, stream>>>(pblock_t, gs_[l], bes_[l], sc, sh);
        curIn = agg;
        curScale = sc;
        curShift = sh;
    }

    pool_k<<<(NN + POOL_CHUNK - 1) / POOL_CHUNK, 256, 0, stream>>>(
        aggA, curScale, curShift, batch, pooled);
    mlp_k<<<NG, 128, 0, stream>>>(pooled, batch, Wm1, bm1, Wm2, bm2, Wm3, bm3,
                                  Wm4, bm4, out);
}